// Round 4
// baseline (349.365 us; speedup 1.0000x reference)
//
#include <hip/hip_runtime.h>
#include <cstdint>
#include <cstddef>

typedef __bf16 bf16x8 __attribute__((ext_vector_type(8)));
typedef float f32x4 __attribute__((ext_vector_type(4)));
typedef unsigned short u16;
typedef unsigned int u32;

static constexpr int T = 2048;
static constexpr int DM = 1024;
// 1/(32*ln2) = log2(e)/32 : folded into W_Q so attention needs only exp2
static constexpr float QSCALE = 0.04508422f;

#define GLOBAL_AS __attribute__((address_space(1)))
#define LDS_AS __attribute__((address_space(3)))

__device__ __forceinline__ void gld_lds16(const u16* g, u16* l) {
  __builtin_amdgcn_global_load_lds((const GLOBAL_AS u32*)g, (LDS_AS u32*)l, 16, 0, 0);
}

__device__ __forceinline__ u16 f2bf(float f) {
  u32 u = __builtin_bit_cast(u32, f);
  u += 0x7fffu + ((u >> 16) & 1u);
  return (u16)(u >> 16);
}

// pack two fp32 -> 2 bf16 in one dword
__device__ __forceinline__ u32 pkb(float lo, float hi) {
#if __has_builtin(__builtin_amdgcn_cvt_pk_bf16_f32)
  typedef __bf16 bf16x2 __attribute__((ext_vector_type(2)));
  bf16x2 r = __builtin_amdgcn_cvt_pk_bf16_f32(lo, hi);
  return __builtin_bit_cast(u32, r);
#else
  return __builtin_amdgcn_perm(__builtin_bit_cast(u32, hi),
                               __builtin_bit_cast(u32, lo), 0x07060302u);
#endif
}

__device__ __forceinline__ float fexp2(float x) {
#if __has_builtin(__builtin_amdgcn_exp2f)
  return __builtin_amdgcn_exp2f(x);
#else
  return __builtin_exp2f(x);
#endif
}

// ---------------- X fp32 -> bf16 convert (once) ---------------------------------------
__global__ __launch_bounds__(256) void xcvt(
    const float* __restrict__ q, const float* __restrict__ k, const float* __restrict__ v,
    u16* __restrict__ oq, u16* __restrict__ ok, u16* __restrict__ ov) {
  const float* X = blockIdx.y == 0 ? q : blockIdx.y == 1 ? k : v;
  u16* O = blockIdx.y == 0 ? oq : blockIdx.y == 1 ? ok : ov;
  const size_t i = ((size_t)blockIdx.x * 256 + threadIdx.x) * 8;
  float4 a0 = *(const float4*)(X + i), a1 = *(const float4*)(X + i + 4);
  uint4 p;
  p.x = pkb(a0.x, a0.y); p.y = pkb(a0.z, a0.w);
  p.z = pkb(a1.x, a1.y); p.w = pkb(a1.z, a1.w);
  *(uint4*)(O + i) = p;
}

// ---------------- Weight transpose + convert: Wt[n][k] bf16 from W[k][n] fp32 --------
__global__ __launch_bounds__(256) void wt_kernel(
    const float* __restrict__ W0, const float* __restrict__ W1, const float* __restrict__ W2,
    u16* __restrict__ O0, u16* __restrict__ O1, u16* __restrict__ O2) {
  const float* W = blockIdx.z == 0 ? W0 : blockIdx.z == 1 ? W1 : W2;
  u16* O = blockIdx.z == 0 ? O0 : blockIdx.z == 1 ? O1 : O2;
  const float sc = blockIdx.z == 0 ? QSCALE : 1.0f;
  const int k0 = blockIdx.x * 64, n0 = blockIdx.y * 64;
  __shared__ float tile[64][68];
  const int tid = threadIdx.x;
#pragma unroll
  for (int it = 0; it < 4; ++it) {
    int chunk = tid + it * 256;
    int r = chunk >> 4, c4 = (chunk & 15) * 4;
    *(float4*)&tile[r][c4] = *(const float4*)(W + (size_t)(k0 + r) * DM + n0 + c4);
  }
  __syncthreads();
#pragma unroll
  for (int it = 0; it < 4; ++it) {
    int chunk = tid + it * 256;
    int n = chunk >> 4, k4 = (chunk & 15) * 4;
    ushort4 o;
    o.x = f2bf(tile[k4 + 0][n] * sc);
    o.y = f2bf(tile[k4 + 1][n] * sc);
    o.z = f2bf(tile[k4 + 2][n] * sc);
    o.w = f2bf(tile[k4 + 3][n] * sc);
    *(ushort4*)(O + (size_t)(n0 + n) * DM + k0 + k4) = o;
  }
}

// ---------------- Projection GEMM: BK=64, XCD-stripe swizzle, fused V-transpose -------
// blockIdx.x in [0,512): xcd = x&7 owns m-stripe [xcd*1024, +1024) so its A panel
// (2.1 MB) + W (2 MB) stay L2-resident across the 8 n-blocks. z=2 writes VHt[bh][d][t].
__global__ __launch_bounds__(256, 3) void gemm_proj(
    const u16* __restrict__ Xq, const u16* __restrict__ Xk, const u16* __restrict__ Xv,
    const u16* __restrict__ Wq, const u16* __restrict__ Wk, const u16* __restrict__ Wv,
    u16* __restrict__ Oq, u16* __restrict__ Ok, u16* __restrict__ VHt) {
  const int z = blockIdx.y;
  const u16* X = z == 0 ? Xq : z == 1 ? Xk : Xv;    // [M][K] bf16
  const u16* Wt = z == 0 ? Wq : z == 1 ? Wk : Wv;   // [N][K] bf16
  const int xcd = blockIdx.x & 7, j = blockIdx.x >> 3;
  const int n0 = (j & 7) * 128;
  const int m0 = (xcd * 8 + (j >> 3)) * 128;
  __shared__ u16 Al[128][64];   // unpadded; chunk c of row r stored at c^(r&7)
  __shared__ u16 Bl[128][64];
  const int tid = threadIdx.x, w = tid >> 6, lane = tid & 63;
  const int c16 = lane & 15, quad = lane >> 4;
  const int wm = (w >> 1) * 64, wn = (w & 1) * 64;
  const int rk = lane >> 3;                    // row-in-8 for DMA
  const int ck = ((lane & 7) ^ rk) * 8;        // swizzled global chunk
  const int swz = c16 & 7;
  f32x4 acc[4][4] = {};
  const u16* ga = X + (size_t)(m0 + w * 32 + rk) * DM + ck;
  const u16* gb = Wt + (size_t)(n0 + w * 32 + rk) * DM + ck;
  for (int kk = 0; kk < 1024; kk += 64) {
    __syncthreads();
#pragma unroll
    for (int i = 0; i < 4; ++i) {
      gld_lds16(ga + kk + (size_t)(i * 8) * DM, &Al[w * 32 + i * 8][0]);
      gld_lds16(gb + kk + (size_t)(i * 8) * DM, &Bl[w * 32 + i * 8][0]);
    }
    __syncthreads();
#pragma unroll
    for (int s = 0; s < 2; ++s) {
      bf16x8 af[4], bfr[4];
#pragma unroll
      for (int t = 0; t < 4; ++t) af[t] = *(const bf16x8*)&Al[wm + t * 16 + c16][((quad + 4 * s) ^ swz) * 8];
#pragma unroll
      for (int t = 0; t < 4; ++t) bfr[t] = *(const bf16x8*)&Bl[wn + t * 16 + c16][((quad + 4 * s) ^ swz) * 8];
#pragma unroll
      for (int mt = 0; mt < 4; ++mt)
#pragma unroll
        for (int nt = 0; nt < 4; ++nt)
          acc[mt][nt] = __builtin_amdgcn_mfma_f32_16x16x32_bf16(af[mt], bfr[nt], acc[mt][nt], 0, 0, 0);
    }
  }
  if (z < 2) {
    u16* O = z == 0 ? Oq : Ok;
#pragma unroll
    for (int mt = 0; mt < 4; ++mt)
#pragma unroll
      for (int nt = 0; nt < 4; ++nt)
#pragma unroll
        for (int r = 0; r < 4; ++r) {
          size_t row = m0 + wm + mt * 16 + quad * 4 + r;
          size_t col = n0 + wn + nt * 16 + c16;
          O[row * DM + col] = f2bf(acc[mt][nt][r]);
        }
  } else {
    // V slice: write transposed VHt[bh][d][t]; the 4 r-values are consecutive t.
#pragma unroll
    for (int mt = 0; mt < 4; ++mt)
#pragma unroll
      for (int nt = 0; nt < 4; ++nt) {
        const int row0 = m0 + wm + mt * 16 + quad * 4;
        const int col = n0 + wn + nt * 16 + c16;
        const int bb = row0 >> 11, t0 = row0 & 2047;
        const int hh = col >> 6, dd = col & 63;
        ushort4 o;
        o.x = f2bf(acc[mt][nt][0]);
        o.y = f2bf(acc[mt][nt][1]);
        o.z = f2bf(acc[mt][nt][2]);
        o.w = f2bf(acc[mt][nt][3]);
        *(ushort4*)(VHt + ((size_t)((bb * 16 + hh) * 64 + dd)) * T + t0) = o;
      }
  }
}

// ---------------- Flash attention + residual, S^T form, 64 q-rows per wave ------------
// 512 blocks = 64 bh x 8 q-blocks of 256 rows; 4 waves x 64 q (4 q-tiles of 16).
// LDS ~50 KB + regs scoped for 3 blocks/CU. P goes through XOR-swizzled unpadded
// Pl[w][qi][16][64] (writes uniform 4-way = b64 minimum; reads 2-way = free).
__global__ __launch_bounds__(256, 3) void flash_kernel(
    const u16* __restrict__ QH, const u16* __restrict__ KH, const u16* __restrict__ VHt,
    const float* __restrict__ res, float* __restrict__ out) {
  const int blk = blockIdx.x;
  const int x = blk & 7, g = blk >> 3;
  const int bh = x * 8 + (g & 7);          // XCD x owns heads 8x..8x+7 (K/V ~4MB = L2)
  const int qb = g >> 3;
  const int b = bh >> 4, h = bh & 15;
  const int tid = threadIdx.x, w = tid >> 6, lane = tid & 63;
  const int c16 = lane & 15, quad = lane >> 4;
  const int swzq = c16 & 7;
  __shared__ u16 Kl[64][64];               // [k][d], swizzled chunks
  __shared__ u16 Vt[64][64];               // [d][k], swizzled chunks
  __shared__ u16 Pl[4][4][16][64];         // [wave][qi][q][k], swizzled chunks
  __shared__ float Ll[4][4][16];
  const int qbase = qb * 256 + w * 64;
  bf16x8 bq[4][2];                         // B-frags of Q (resident)
#pragma unroll
  for (int qi = 0; qi < 4; ++qi) {
    const u16* qp = QH + (size_t)(b * T + qbase + qi * 16 + c16) * DM + h * 64 + quad * 8;
    bq[qi][0] = *(const bf16x8*)qp;
    bq[qi][1] = *(const bf16x8*)(qp + 32);
  }
  f32x4 acc[4][4] = {};                    // [qi][nt]
  float rs[4] = {0.f, 0.f, 0.f, 0.f};
  const int rk = lane >> 3;
  const int ck8 = ((lane & 7) ^ rk) * 8;
  const u16* kg = KH + (size_t)(b * T) * DM + h * 64 + ck8;
  const u16* vg = VHt + ((size_t)bh * 64 + w * 16 + rk) * T + ck8;
  for (int kt = 0; kt < 32; ++kt) {
    __syncthreads();
    {
      const u16* kg0 = kg + (size_t)(kt * 64 + w * 16 + rk) * DM;
      gld_lds16(kg0, &Kl[w * 16][0]);
      gld_lds16(kg0 + (size_t)8 * DM, &Kl[w * 16 + 8][0]);
      const u16* vg0 = vg + kt * 64;
      gld_lds16(vg0, &Vt[w * 16][0]);
      gld_lds16(vg0 + (size_t)8 * T, &Vt[w * 16 + 8][0]);
    }
    __syncthreads();
    // ---- Phase A: S^T = K Q^T, exp2, pack P (ak dies here) ----
    {
      bf16x8 ak[4][2];
#pragma unroll
      for (int mt = 0; mt < 4; ++mt) {
        const int r = mt * 16 + c16;
        ak[mt][0] = *(const bf16x8*)&Kl[r][(quad ^ swzq) * 8];
        ak[mt][1] = *(const bf16x8*)&Kl[r][((4 + quad) ^ swzq) * 8];
      }
#pragma unroll
      for (int qi = 0; qi < 4; ++qi) {
#pragma unroll
        for (int mt = 0; mt < 4; ++mt) {
          f32x4 st = {};
          st = __builtin_amdgcn_mfma_f32_16x16x32_bf16(ak[mt][0], bq[qi][0], st, 0, 0, 0);
          st = __builtin_amdgcn_mfma_f32_16x16x32_bf16(ak[mt][1], bq[qi][1], st, 0, 0, 0);
          const float p0 = fexp2(st[0]), p1 = fexp2(st[1]);
          const float p2 = fexp2(st[2]), p3 = fexp2(st[3]);
          rs[qi] += (p0 + p1) + (p2 + p3);
          uint2 pw;
          pw.x = pkb(p0, p1);
          pw.y = pkb(p2, p3);
          const int col = (((mt * 2 + (quad >> 1)) ^ swzq) * 8) + (quad & 1) * 4;
          *(uint2*)&Pl[w][qi][c16][col] = pw;
        }
      }
    }
    asm volatile("s_waitcnt lgkmcnt(0)" ::: "memory");  // P writes visible (same wave)
    // ---- Phase B: O += P V (ap preloaded, bv streamed per nt) ----
    bf16x8 ap[4][2];
#pragma unroll
    for (int qi = 0; qi < 4; ++qi) {
      ap[qi][0] = *(const bf16x8*)&Pl[w][qi][c16][(quad ^ swzq) * 8];
      ap[qi][1] = *(const bf16x8*)&Pl[w][qi][c16][((4 + quad) ^ swzq) * 8];
    }
#pragma unroll
    for (int nt = 0; nt < 4; ++nt) {
      const int r = nt * 16 + c16;
      const bf16x8 bv0 = *(const bf16x8*)&Vt[r][(quad ^ swzq) * 8];
      const bf16x8 bv1 = *(const bf16x8*)&Vt[r][((4 + quad) ^ swzq) * 8];
#pragma unroll
      for (int qi = 0; qi < 4; ++qi) {
        acc[qi][nt] = __builtin_amdgcn_mfma_f32_16x16x32_bf16(ap[qi][0], bv0, acc[qi][nt], 0, 0, 0);
        acc[qi][nt] = __builtin_amdgcn_mfma_f32_16x16x32_bf16(ap[qi][1], bv1, acc[qi][nt], 0, 0, 0);
      }
    }
  }
  // softmax denominators: reduce over quads, broadcast via LDS
#pragma unroll
  for (int qi = 0; qi < 4; ++qi) {
    float t = rs[qi];
    t += __shfl_xor(t, 16, 64);
    t += __shfl_xor(t, 32, 64);
    if (quad == 0) Ll[w][qi][c16] = t;
  }
  asm volatile("s_waitcnt lgkmcnt(0)" ::: "memory");
#pragma unroll
  for (int qi = 0; qi < 4; ++qi) {
    const f32x4 lv = *(const f32x4*)&Ll[w][qi][quad * 4];
#pragma unroll
    for (int r = 0; r < 4; ++r) {
      const float inv = 1.0f / lv[r];
      const size_t rowbase = (size_t)(b * T + qbase + qi * 16 + quad * 4 + r) * DM + h * 64;
#pragma unroll
      for (int nt = 0; nt < 4; ++nt) {
        const size_t idx = rowbase + nt * 16 + c16;
        out[idx] = acc[qi][nt][r] * inv + res[idx];
      }
    }
  }
}

extern "C" void kernel_launch(void* const* d_in, const int* in_sizes, int n_in,
                              void* d_out, int out_size, void* d_ws, size_t ws_size,
                              hipStream_t stream) {
  const float* q = (const float*)d_in[0];
  const float* k = (const float*)d_in[1];
  const float* v = (const float*)d_in[2];
  const float* WQ = (const float*)d_in[3];
  const float* WK = (const float*)d_in[4];
  const float* WV = (const float*)d_in[5];
  char* ws = (char*)d_ws;
  const size_t PH = (size_t)8192 * 1024 * 2;   // bf16 activation buffer bytes
  const size_t WT = (size_t)1024 * 1024 * 2;
  // d_out doubles as scratch for 2 of the 3 bf16 X tensors (fully rewritten by flash).
  u16* XqB = (u16*)d_out;
  u16* XkB = (u16*)d_out + (size_t)8192 * 1024;
  u16* XvB = (u16*)(ws);
  u16* WtQ = (u16*)(ws + PH);
  u16* WtK = (u16*)(ws + PH + WT);
  u16* WtV = (u16*)(ws + PH + 2 * WT);
  u16* QH  = (u16*)(ws + PH + 3 * WT);
  u16* KH  = (u16*)(ws + 2 * PH + 3 * WT);
  u16* VHt = (u16*)(ws + 3 * PH + 3 * WT);

  xcvt<<<dim3(4096, 3), 256, 0, stream>>>(q, k, v, XqB, XkB, XvB);
  wt_kernel<<<dim3(16, 16, 3), 256, 0, stream>>>(WQ, WK, WV, WtQ, WtK, WtV);
  gemm_proj<<<dim3(512, 3), 256, 0, stream>>>(XqB, XkB, XvB, WtQ, WtK, WtV, QH, KH, VHt);
  flash_kernel<<<512, 256, 0, stream>>>(QH, KH, VHt, q, (float*)d_out);
}

// Round 5
// 330.501 us; speedup vs baseline: 1.0571x; 1.0571x over previous
//
#include <hip/hip_runtime.h>
#include <cstdint>
#include <cstddef>

typedef __bf16 bf16x8 __attribute__((ext_vector_type(8)));
typedef float f32x4 __attribute__((ext_vector_type(4)));
typedef unsigned short u16;
typedef unsigned int u32;

static constexpr int T = 2048;
static constexpr int DM = 1024;
// 1/(32*ln2) = log2(e)/32 : folded into W_Q so attention needs only exp2
static constexpr float QSCALE = 0.04508422f;

#define GLOBAL_AS __attribute__((address_space(1)))
#define LDS_AS __attribute__((address_space(3)))

__device__ __forceinline__ void gld_lds16(const u16* g, u16* l) {
  __builtin_amdgcn_global_load_lds((const GLOBAL_AS u32*)g, (LDS_AS u32*)l, 16, 0, 0);
}

__device__ __forceinline__ u16 f2bf(float f) {
  u32 u = __builtin_bit_cast(u32, f);
  u += 0x7fffu + ((u >> 16) & 1u);
  return (u16)(u >> 16);
}

// pack two fp32 -> 2 bf16 in one dword
__device__ __forceinline__ u32 pkb(float lo, float hi) {
#if __has_builtin(__builtin_amdgcn_cvt_pk_bf16_f32)
  typedef __bf16 bf16x2 __attribute__((ext_vector_type(2)));
  bf16x2 r = __builtin_amdgcn_cvt_pk_bf16_f32(lo, hi);
  return __builtin_bit_cast(u32, r);
#else
  return __builtin_amdgcn_perm(__builtin_bit_cast(u32, hi),
                               __builtin_bit_cast(u32, lo), 0x07060302u);
#endif
}

__device__ __forceinline__ float fexp2(float x) {
#if __has_builtin(__builtin_amdgcn_exp2f)
  return __builtin_amdgcn_exp2f(x);
#else
  return __builtin_exp2f(x);
#endif
}

// ---------------- X fp32 -> bf16 convert (once) ---------------------------------------
__global__ __launch_bounds__(256) void xcvt(
    const float* __restrict__ q, const float* __restrict__ k, const float* __restrict__ v,
    u16* __restrict__ oq, u16* __restrict__ ok, u16* __restrict__ ov) {
  const float* X = blockIdx.y == 0 ? q : blockIdx.y == 1 ? k : v;
  u16* O = blockIdx.y == 0 ? oq : blockIdx.y == 1 ? ok : ov;
  const size_t i = ((size_t)blockIdx.x * 256 + threadIdx.x) * 8;
  float4 a0 = *(const float4*)(X + i), a1 = *(const float4*)(X + i + 4);
  uint4 p;
  p.x = pkb(a0.x, a0.y); p.y = pkb(a0.z, a0.w);
  p.z = pkb(a1.x, a1.y); p.w = pkb(a1.z, a1.w);
  *(uint4*)(O + i) = p;
}

// ---------------- Weight transpose + convert: Wt[n][k] bf16 from W[k][n] fp32 --------
__global__ __launch_bounds__(256) void wt_kernel(
    const float* __restrict__ W0, const float* __restrict__ W1, const float* __restrict__ W2,
    u16* __restrict__ O0, u16* __restrict__ O1, u16* __restrict__ O2) {
  const float* W = blockIdx.z == 0 ? W0 : blockIdx.z == 1 ? W1 : W2;
  u16* O = blockIdx.z == 0 ? O0 : blockIdx.z == 1 ? O1 : O2;
  const float sc = blockIdx.z == 0 ? QSCALE : 1.0f;
  const int k0 = blockIdx.x * 64, n0 = blockIdx.y * 64;
  __shared__ float tile[64][68];
  const int tid = threadIdx.x;
#pragma unroll
  for (int it = 0; it < 4; ++it) {
    int chunk = tid + it * 256;
    int r = chunk >> 4, c4 = (chunk & 15) * 4;
    *(float4*)&tile[r][c4] = *(const float4*)(W + (size_t)(k0 + r) * DM + n0 + c4);
  }
  __syncthreads();
#pragma unroll
  for (int it = 0; it < 4; ++it) {
    int chunk = tid + it * 256;
    int n = chunk >> 4, k4 = (chunk & 15) * 4;
    ushort4 o;
    o.x = f2bf(tile[k4 + 0][n] * sc);
    o.y = f2bf(tile[k4 + 1][n] * sc);
    o.z = f2bf(tile[k4 + 2][n] * sc);
    o.w = f2bf(tile[k4 + 3][n] * sc);
    *(ushort4*)(O + (size_t)(n0 + n) * DM + k0 + k4) = o;
  }
}

// ---------------- Projection GEMM: BK=64, XCD-stripe swizzle, fused V-transpose -------
__global__ __launch_bounds__(256, 3) void gemm_proj(
    const u16* __restrict__ Xq, const u16* __restrict__ Xk, const u16* __restrict__ Xv,
    const u16* __restrict__ Wq, const u16* __restrict__ Wk, const u16* __restrict__ Wv,
    u16* __restrict__ Oq, u16* __restrict__ Ok, u16* __restrict__ VHt) {
  const int z = blockIdx.y;
  const u16* X = z == 0 ? Xq : z == 1 ? Xk : Xv;    // [M][K] bf16
  const u16* Wt = z == 0 ? Wq : z == 1 ? Wk : Wv;   // [N][K] bf16
  const int xcd = blockIdx.x & 7, j = blockIdx.x >> 3;
  const int n0 = (j & 7) * 128;
  const int m0 = (xcd * 8 + (j >> 3)) * 128;
  __shared__ u16 Al[128][64];   // unpadded; chunk c of row r stored at c^(r&7)
  __shared__ u16 Bl[128][64];
  const int tid = threadIdx.x, w = tid >> 6, lane = tid & 63;
  const int c16 = lane & 15, quad = lane >> 4;
  const int wm = (w >> 1) * 64, wn = (w & 1) * 64;
  const int rk = lane >> 3;                    // row-in-8 for DMA
  const int ck = ((lane & 7) ^ rk) * 8;        // swizzled global chunk
  const int swz = c16 & 7;
  f32x4 acc[4][4] = {};
  const u16* ga = X + (size_t)(m0 + w * 32 + rk) * DM + ck;
  const u16* gb = Wt + (size_t)(n0 + w * 32 + rk) * DM + ck;
  for (int kk = 0; kk < 1024; kk += 64) {
    __syncthreads();
#pragma unroll
    for (int i = 0; i < 4; ++i) {
      gld_lds16(ga + kk + (size_t)(i * 8) * DM, &Al[w * 32 + i * 8][0]);
      gld_lds16(gb + kk + (size_t)(i * 8) * DM, &Bl[w * 32 + i * 8][0]);
    }
    __syncthreads();
#pragma unroll
    for (int s = 0; s < 2; ++s) {
      bf16x8 af[4], bfr[4];
#pragma unroll
      for (int t = 0; t < 4; ++t) af[t] = *(const bf16x8*)&Al[wm + t * 16 + c16][((quad + 4 * s) ^ swz) * 8];
#pragma unroll
      for (int t = 0; t < 4; ++t) bfr[t] = *(const bf16x8*)&Bl[wn + t * 16 + c16][((quad + 4 * s) ^ swz) * 8];
#pragma unroll
      for (int mt = 0; mt < 4; ++mt)
#pragma unroll
        for (int nt = 0; nt < 4; ++nt)
          acc[mt][nt] = __builtin_amdgcn_mfma_f32_16x16x32_bf16(af[mt], bfr[nt], acc[mt][nt], 0, 0, 0);
    }
  }
  if (z < 2) {
    u16* O = z == 0 ? Oq : Ok;
#pragma unroll
    for (int mt = 0; mt < 4; ++mt)
#pragma unroll
      for (int nt = 0; nt < 4; ++nt)
#pragma unroll
        for (int r = 0; r < 4; ++r) {
          size_t row = m0 + wm + mt * 16 + quad * 4 + r;
          size_t col = n0 + wn + nt * 16 + c16;
          O[row * DM + col] = f2bf(acc[mt][nt][r]);
        }
  } else {
    // V slice: write transposed VHt[bh][d][t]; the 4 r-values are consecutive t.
#pragma unroll
    for (int mt = 0; mt < 4; ++mt)
#pragma unroll
      for (int nt = 0; nt < 4; ++nt) {
        const int row0 = m0 + wm + mt * 16 + quad * 4;
        const int col = n0 + wn + nt * 16 + c16;
        const int bb = row0 >> 11, t0 = row0 & 2047;
        const int hh = col >> 6, dd = col & 63;
        ushort4 o;
        o.x = f2bf(acc[mt][nt][0]);
        o.y = f2bf(acc[mt][nt][1]);
        o.z = f2bf(acc[mt][nt][2]);
        o.w = f2bf(acc[mt][nt][3]);
        *(ushort4*)(VHt + ((size_t)((bb * 16 + hh) * 64 + dd)) * T + t0) = o;
      }
  }
}

// ---------------- Flash attention + residual, S^T form, 64 q-rows per wave ------------
// 512 blocks (= 2 blocks/CU, the occupancy ceiling for this grid — launch_bounds(256,2),
// do NOT squeeze registers further; (256,3) spilled in round 4). 128-row K/V tiles
// staged via REGISTER prefetch (plain dwordx4 loads stay in flight across barriers,
// unlike global_load_lds which forces a vmcnt(0) drain) -> 16 barrier rounds, 2 k-halves
// per round. XOR-swizzled unpadded LDS, P round-trip per wave.
__global__ __launch_bounds__(256, 2) void flash_kernel(
    const u16* __restrict__ QH, const u16* __restrict__ KH, const u16* __restrict__ VHt,
    const float* __restrict__ res, float* __restrict__ out) {
  const int blk = blockIdx.x;
  const int x = blk & 7, g = blk >> 3;
  const int bh = x * 8 + (g & 7);          // XCD x owns heads 8x..8x+7 (K/V ~4MB = L2)
  const int qb = g >> 3;
  const int b = bh >> 4, h = bh & 15;
  const int tid = threadIdx.x, w = tid >> 6, lane = tid & 63;
  const int c16 = lane & 15, quad = lane >> 4;
  const int swzq = c16 & 7;
  __shared__ u16 Kl[128][64];              // [k][d], chunk c of row r at c^(r&7)
  __shared__ u16 Vt[64][128];              // [d][k], chunk c (of 16) at c^(r&7) (low 3 bits)
  __shared__ u16 Pl[4][4][16][64];         // [wave][qi][q][k], swizzled chunks
  __shared__ float Ll[4][4][16];
  const int qbase = qb * 256 + w * 64;
  bf16x8 bq[4][2];                         // B-frags of Q (resident)
#pragma unroll
  for (int qi = 0; qi < 4; ++qi) {
    const u16* qp = QH + (size_t)(b * T + qbase + qi * 16 + c16) * DM + h * 64 + quad * 8;
    bq[qi][0] = *(const bf16x8*)qp;
    bq[qi][1] = *(const bf16x8*)(qp + 32);
  }
  f32x4 acc[4][4] = {};                    // [qi][nt]
  float rs[4] = {0.f, 0.f, 0.f, 0.f};
  // --- staging maps (per thread): K rows rK+32i (128), V rows rV+16i (64) ---
  const int rK = tid >> 3, cK = tid & 7;     // K: 8 chunks/row
  const int rV = tid >> 4, cV = tid & 15;    // V: 16 chunks/row
  const int skc = (cK ^ (rK & 7)) * 8;       // swizzled LDS col (constant over i)
  const int svc = (cV ^ (rV & 7)) * 8;
  const u16* kgp = KH + (size_t)(b * T + rK) * DM + h * 64 + cK * 8;
  const u16* vgp = VHt + ((size_t)bh * 64 + rV) * T + cV * 8;
  uint4 kr[4], vr[4];
#pragma unroll
  for (int i = 0; i < 4; ++i) {
    kr[i] = *(const uint4*)(kgp + (size_t)(32 * i) * DM);
    vr[i] = *(const uint4*)(vgp + (size_t)(16 * i) * T);
  }
  for (int ot = 0; ot < 16; ++ot) {
    __syncthreads();                       // everyone done reading previous tile
#pragma unroll
    for (int i = 0; i < 4; ++i) {
      *(uint4*)&Kl[rK + 32 * i][skc] = kr[i];
      *(uint4*)&Vt[rV + 16 * i][svc] = vr[i];
    }
    if (ot < 15) {                         // prefetch next tile into registers
#pragma unroll
      for (int i = 0; i < 4; ++i) {
        kr[i] = *(const uint4*)(kgp + (size_t)((ot + 1) * 128 + 32 * i) * DM);
        vr[i] = *(const uint4*)(vgp + (size_t)(16 * i) * T + (ot + 1) * 128);
      }
    }
    __syncthreads();                       // tile visible to all waves
#pragma unroll
    for (int hh = 0; hh < 2; ++hh) {
      // ---- Phase A: S^T = K Q^T, exp2, pack P ----
      {
        bf16x8 ak[4][2];
#pragma unroll
        for (int mt = 0; mt < 4; ++mt) {
          const int r = hh * 64 + mt * 16 + c16;
          ak[mt][0] = *(const bf16x8*)&Kl[r][(quad ^ swzq) * 8];
          ak[mt][1] = *(const bf16x8*)&Kl[r][((4 + quad) ^ swzq) * 8];
        }
#pragma unroll
        for (int qi = 0; qi < 4; ++qi) {
#pragma unroll
          for (int mt = 0; mt < 4; ++mt) {
            f32x4 st = {};
            st = __builtin_amdgcn_mfma_f32_16x16x32_bf16(ak[mt][0], bq[qi][0], st, 0, 0, 0);
            st = __builtin_amdgcn_mfma_f32_16x16x32_bf16(ak[mt][1], bq[qi][1], st, 0, 0, 0);
            const float p0 = fexp2(st[0]), p1 = fexp2(st[1]);
            const float p2 = fexp2(st[2]), p3 = fexp2(st[3]);
            rs[qi] += (p0 + p1) + (p2 + p3);
            uint2 pw;
            pw.x = pkb(p0, p1);
            pw.y = pkb(p2, p3);
            const int col = (((mt * 2 + (quad >> 1)) ^ swzq) * 8) + (quad & 1) * 4;
            *(uint2*)&Pl[w][qi][c16][col] = pw;
          }
        }
      }
      asm volatile("s_waitcnt lgkmcnt(0)" ::: "memory");  // P visible (same wave)
      // ---- Phase B: O += P V ----
      bf16x8 ap[4][2];
#pragma unroll
      for (int qi = 0; qi < 4; ++qi) {
        ap[qi][0] = *(const bf16x8*)&Pl[w][qi][c16][(quad ^ swzq) * 8];
        ap[qi][1] = *(const bf16x8*)&Pl[w][qi][c16][((4 + quad) ^ swzq) * 8];
      }
#pragma unroll
      for (int nt = 0; nt < 4; ++nt) {
        const int r = nt * 16 + c16;
        const bf16x8 bv0 = *(const bf16x8*)&Vt[r][(hh * 8 + (quad ^ swzq)) * 8];
        const bf16x8 bv1 = *(const bf16x8*)&Vt[r][(hh * 8 + ((4 + quad) ^ swzq)) * 8];
#pragma unroll
        for (int qi = 0; qi < 4; ++qi) {
          acc[qi][nt] = __builtin_amdgcn_mfma_f32_16x16x32_bf16(ap[qi][0], bv0, acc[qi][nt], 0, 0, 0);
          acc[qi][nt] = __builtin_amdgcn_mfma_f32_16x16x32_bf16(ap[qi][1], bv1, acc[qi][nt], 0, 0, 0);
        }
      }
    }
  }
  // softmax denominators: reduce over quads, broadcast via LDS
#pragma unroll
  for (int qi = 0; qi < 4; ++qi) {
    float t = rs[qi];
    t += __shfl_xor(t, 16, 64);
    t += __shfl_xor(t, 32, 64);
    if (quad == 0) Ll[w][qi][c16] = t;
  }
  asm volatile("s_waitcnt lgkmcnt(0)" ::: "memory");
#pragma unroll
  for (int qi = 0; qi < 4; ++qi) {
    const f32x4 lv = *(const f32x4*)&Ll[w][qi][quad * 4];
#pragma unroll
    for (int r = 0; r < 4; ++r) {
      const float inv = 1.0f / lv[r];
      const size_t rowbase = (size_t)(b * T + qbase + qi * 16 + quad * 4 + r) * DM + h * 64;
#pragma unroll
      for (int nt = 0; nt < 4; ++nt) {
        const size_t idx = rowbase + nt * 16 + c16;
        out[idx] = acc[qi][nt][r] * inv + res[idx];
      }
    }
  }
}

extern "C" void kernel_launch(void* const* d_in, const int* in_sizes, int n_in,
                              void* d_out, int out_size, void* d_ws, size_t ws_size,
                              hipStream_t stream) {
  const float* q = (const float*)d_in[0];
  const float* k = (const float*)d_in[1];
  const float* v = (const float*)d_in[2];
  const float* WQ = (const float*)d_in[3];
  const float* WK = (const float*)d_in[4];
  const float* WV = (const float*)d_in[5];
  char* ws = (char*)d_ws;
  const size_t PH = (size_t)8192 * 1024 * 2;   // bf16 activation buffer bytes
  const size_t WT = (size_t)1024 * 1024 * 2;
  // d_out doubles as scratch for 2 of the 3 bf16 X tensors (fully rewritten by flash).
  u16* XqB = (u16*)d_out;
  u16* XkB = (u16*)d_out + (size_t)8192 * 1024;
  u16* XvB = (u16*)(ws);
  u16* WtQ = (u16*)(ws + PH);
  u16* WtK = (u16*)(ws + PH + WT);
  u16* WtV = (u16*)(ws + PH + 2 * WT);
  u16* QH  = (u16*)(ws + PH + 3 * WT);
  u16* KH  = (u16*)(ws + 2 * PH + 3 * WT);
  u16* VHt = (u16*)(ws + 3 * PH + 3 * WT);

  xcvt<<<dim3(4096, 3), 256, 0, stream>>>(q, k, v, XqB, XkB, XvB);
  wt_kernel<<<dim3(16, 16, 3), 256, 0, stream>>>(WQ, WK, WV, WtQ, WtK, WtV);
  gemm_proj<<<dim3(512, 3), 256, 0, stream>>>(XqB, XkB, XvB, WtQ, WtK, WtV, QH, KH, VHt);
  flash_kernel<<<512, 256, 0, stream>>>(QH, KH, VHt, q, (float*)d_out);
}

// Round 6
// 293.137 us; speedup vs baseline: 1.1918x; 1.1275x over previous
//
#include <hip/hip_runtime.h>
#include <cstdint>
#include <cstddef>

typedef __bf16 bf16x8 __attribute__((ext_vector_type(8)));
typedef float f32x4 __attribute__((ext_vector_type(4)));
typedef unsigned short u16;
typedef unsigned int u32;

static constexpr int T = 2048;
static constexpr int DM = 1024;
// 1/(32*ln2) = log2(e)/32 : folded into W_Q so attention needs only exp2
static constexpr float QSCALE = 0.04508422f;

#define GLOBAL_AS __attribute__((address_space(1)))
#define LDS_AS __attribute__((address_space(3)))

__device__ __forceinline__ void gld_lds16(const u16* g, u16* l) {
  __builtin_amdgcn_global_load_lds((const GLOBAL_AS u32*)g, (LDS_AS u32*)l, 16, 0, 0);
}

__device__ __forceinline__ u16 f2bf(float f) {
  u32 u = __builtin_bit_cast(u32, f);
  u += 0x7fffu + ((u >> 16) & 1u);
  return (u16)(u >> 16);
}

// pack two fp32 -> 2 bf16 in one dword
__device__ __forceinline__ u32 pkb(float lo, float hi) {
#if __has_builtin(__builtin_amdgcn_cvt_pk_bf16_f32)
  typedef __bf16 bf16x2 __attribute__((ext_vector_type(2)));
  bf16x2 r = __builtin_amdgcn_cvt_pk_bf16_f32(lo, hi);
  return __builtin_bit_cast(u32, r);
#else
  return __builtin_amdgcn_perm(__builtin_bit_cast(u32, hi),
                               __builtin_bit_cast(u32, lo), 0x07060302u);
#endif
}

__device__ __forceinline__ float fexp2(float x) {
#if __has_builtin(__builtin_amdgcn_exp2f)
  return __builtin_amdgcn_exp2f(x);
#else
  return __builtin_exp2f(x);
#endif
}

// ---------------- X fp32 -> bf16 convert (once) ---------------------------------------
__global__ __launch_bounds__(256) void xcvt(
    const float* __restrict__ q, const float* __restrict__ k, const float* __restrict__ v,
    u16* __restrict__ oq, u16* __restrict__ ok, u16* __restrict__ ov) {
  const float* X = blockIdx.y == 0 ? q : blockIdx.y == 1 ? k : v;
  u16* O = blockIdx.y == 0 ? oq : blockIdx.y == 1 ? ok : ov;
  const size_t i = ((size_t)blockIdx.x * 256 + threadIdx.x) * 8;
  float4 a0 = *(const float4*)(X + i), a1 = *(const float4*)(X + i + 4);
  uint4 p;
  p.x = pkb(a0.x, a0.y); p.y = pkb(a0.z, a0.w);
  p.z = pkb(a1.x, a1.y); p.w = pkb(a1.z, a1.w);
  *(uint4*)(O + i) = p;
}

// ---------------- Weight transpose + convert: Wt[n][k] bf16 from W[k][n] fp32 --------
__global__ __launch_bounds__(256) void wt_kernel(
    const float* __restrict__ W0, const float* __restrict__ W1, const float* __restrict__ W2,
    u16* __restrict__ O0, u16* __restrict__ O1, u16* __restrict__ O2) {
  const float* W = blockIdx.z == 0 ? W0 : blockIdx.z == 1 ? W1 : W2;
  u16* O = blockIdx.z == 0 ? O0 : blockIdx.z == 1 ? O1 : O2;
  const float sc = blockIdx.z == 0 ? QSCALE : 1.0f;
  const int k0 = blockIdx.x * 64, n0 = blockIdx.y * 64;
  __shared__ float tile[64][68];
  const int tid = threadIdx.x;
#pragma unroll
  for (int it = 0; it < 4; ++it) {
    int chunk = tid + it * 256;
    int r = chunk >> 4, c4 = (chunk & 15) * 4;
    *(float4*)&tile[r][c4] = *(const float4*)(W + (size_t)(k0 + r) * DM + n0 + c4);
  }
  __syncthreads();
#pragma unroll
  for (int it = 0; it < 4; ++it) {
    int chunk = tid + it * 256;
    int n = chunk >> 4, k4 = (chunk & 15) * 4;
    ushort4 o;
    o.x = f2bf(tile[k4 + 0][n] * sc);
    o.y = f2bf(tile[k4 + 1][n] * sc);
    o.z = f2bf(tile[k4 + 2][n] * sc);
    o.w = f2bf(tile[k4 + 3][n] * sc);
    *(ushort4*)(O + (size_t)(n0 + n) * DM + k0 + k4) = o;
  }
}

// ---------------- Projection GEMM: BK=64, XCD-stripe swizzle, fused V-transpose -------
__global__ __launch_bounds__(256, 3) void gemm_proj(
    const u16* __restrict__ Xq, const u16* __restrict__ Xk, const u16* __restrict__ Xv,
    const u16* __restrict__ Wq, const u16* __restrict__ Wk, const u16* __restrict__ Wv,
    u16* __restrict__ Oq, u16* __restrict__ Ok, u16* __restrict__ VHt) {
  const int z = blockIdx.y;
  const u16* X = z == 0 ? Xq : z == 1 ? Xk : Xv;    // [M][K] bf16
  const u16* Wt = z == 0 ? Wq : z == 1 ? Wk : Wv;   // [N][K] bf16
  const int xcd = blockIdx.x & 7, j = blockIdx.x >> 3;
  const int n0 = (j & 7) * 128;
  const int m0 = (xcd * 8 + (j >> 3)) * 128;
  __shared__ u16 Al[128][64];   // unpadded; chunk c of row r stored at c^(r&7)
  __shared__ u16 Bl[128][64];
  const int tid = threadIdx.x, w = tid >> 6, lane = tid & 63;
  const int c16 = lane & 15, quad = lane >> 4;
  const int wm = (w >> 1) * 64, wn = (w & 1) * 64;
  const int rk = lane >> 3;                    // row-in-8 for DMA
  const int ck = ((lane & 7) ^ rk) * 8;        // swizzled global chunk
  const int swz = c16 & 7;
  f32x4 acc[4][4] = {};
  const u16* ga = X + (size_t)(m0 + w * 32 + rk) * DM + ck;
  const u16* gb = Wt + (size_t)(n0 + w * 32 + rk) * DM + ck;
  for (int kk = 0; kk < 1024; kk += 64) {
    __syncthreads();
#pragma unroll
    for (int i = 0; i < 4; ++i) {
      gld_lds16(ga + kk + (size_t)(i * 8) * DM, &Al[w * 32 + i * 8][0]);
      gld_lds16(gb + kk + (size_t)(i * 8) * DM, &Bl[w * 32 + i * 8][0]);
    }
    __syncthreads();
#pragma unroll
    for (int s = 0; s < 2; ++s) {
      bf16x8 af[4], bfr[4];
#pragma unroll
      for (int t = 0; t < 4; ++t) af[t] = *(const bf16x8*)&Al[wm + t * 16 + c16][((quad + 4 * s) ^ swz) * 8];
#pragma unroll
      for (int t = 0; t < 4; ++t) bfr[t] = *(const bf16x8*)&Bl[wn + t * 16 + c16][((quad + 4 * s) ^ swz) * 8];
#pragma unroll
      for (int mt = 0; mt < 4; ++mt)
#pragma unroll
        for (int nt = 0; nt < 4; ++nt)
          acc[mt][nt] = __builtin_amdgcn_mfma_f32_16x16x32_bf16(af[mt], bfr[nt], acc[mt][nt], 0, 0, 0);
    }
  }
  if (z < 2) {
    u16* O = z == 0 ? Oq : Ok;
#pragma unroll
    for (int mt = 0; mt < 4; ++mt)
#pragma unroll
      for (int nt = 0; nt < 4; ++nt)
#pragma unroll
        for (int r = 0; r < 4; ++r) {
          size_t row = m0 + wm + mt * 16 + quad * 4 + r;
          size_t col = n0 + wn + nt * 16 + c16;
          O[row * DM + col] = f2bf(acc[mt][nt][r]);
        }
  } else {
    // V slice: write transposed VHt[bh][d][t]; the 4 r-values are consecutive t.
#pragma unroll
    for (int mt = 0; mt < 4; ++mt)
#pragma unroll
      for (int nt = 0; nt < 4; ++nt) {
        const int row0 = m0 + wm + mt * 16 + quad * 4;
        const int col = n0 + wn + nt * 16 + c16;
        const int bb = row0 >> 11, t0 = row0 & 2047;
        const int hh = col >> 6, dd = col & 63;
        ushort4 o;
        o.x = f2bf(acc[mt][nt][0]);
        o.y = f2bf(acc[mt][nt][1]);
        o.z = f2bf(acc[mt][nt][2]);
        o.w = f2bf(acc[mt][nt][3]);
        *(ushort4*)(VHt + ((size_t)((bb * 16 + hh) * 64 + dd)) * T + t0) = o;
      }
  }
}

// ---------------- Flash attention + residual, S^T form, 64 q-rows per wave ------------
// 512 blocks = 2 blocks/CU — this structure's occupancy cap (64 acc + ~128 arch regs;
// (256,3) spilled in r4, register prefetch spilled in r5 — do not add live registers).
// global_load_lds staging (r3-proven), XOR-swizzled unpadded LDS everywhere (r4's
// conflict win), scoped phase A/B register usage.
__global__ __launch_bounds__(256, 2) void flash_kernel(
    const u16* __restrict__ QH, const u16* __restrict__ KH, const u16* __restrict__ VHt,
    const float* __restrict__ res, float* __restrict__ out) {
  const int blk = blockIdx.x;
  const int x = blk & 7, g = blk >> 3;
  const int bh = x * 8 + (g & 7);          // XCD x owns heads 8x..8x+7 (K/V ~4MB = L2)
  const int qb = g >> 3;
  const int b = bh >> 4, h = bh & 15;
  const int tid = threadIdx.x, w = tid >> 6, lane = tid & 63;
  const int c16 = lane & 15, quad = lane >> 4;
  const int swzq = c16 & 7;
  __shared__ u16 Kl[64][64];               // [k][d], chunk c of row r at c^(r&7)
  __shared__ u16 Vt[64][64];               // [d][k], same swizzle
  __shared__ u16 Pl[4][4][16][64];         // [wave][qi][q][k], swizzled chunks
  __shared__ float Ll[4][4][16];
  const int qbase = qb * 256 + w * 64;
  bf16x8 bq[4][2];                         // B-frags of Q (resident)
#pragma unroll
  for (int qi = 0; qi < 4; ++qi) {
    const u16* qp = QH + (size_t)(b * T + qbase + qi * 16 + c16) * DM + h * 64 + quad * 8;
    bq[qi][0] = *(const bf16x8*)qp;
    bq[qi][1] = *(const bf16x8*)(qp + 32);
  }
  f32x4 acc[4][4] = {};                    // [qi][nt]
  float rs[4] = {0.f, 0.f, 0.f, 0.f};
  const int rk = lane >> 3;
  const int ck8 = ((lane & 7) ^ rk) * 8;
  const u16* kg = KH + (size_t)(b * T) * DM + h * 64 + ck8;
  const u16* vg = VHt + ((size_t)bh * 64 + w * 16 + rk) * T + ck8;
  for (int kt = 0; kt < 32; ++kt) {
    __syncthreads();
    {
      const u16* kg0 = kg + (size_t)(kt * 64 + w * 16 + rk) * DM;
      gld_lds16(kg0, &Kl[w * 16][0]);
      gld_lds16(kg0 + (size_t)8 * DM, &Kl[w * 16 + 8][0]);
      const u16* vg0 = vg + kt * 64;
      gld_lds16(vg0, &Vt[w * 16][0]);
      gld_lds16(vg0 + (size_t)8 * T, &Vt[w * 16 + 8][0]);
    }
    __syncthreads();
    // ---- Phase A: S^T = K Q^T, exp2, pack P (ak dies here) ----
    {
      bf16x8 ak[4][2];
#pragma unroll
      for (int mt = 0; mt < 4; ++mt) {
        const int r = mt * 16 + c16;
        ak[mt][0] = *(const bf16x8*)&Kl[r][(quad ^ swzq) * 8];
        ak[mt][1] = *(const bf16x8*)&Kl[r][((4 + quad) ^ swzq) * 8];
      }
#pragma unroll
      for (int qi = 0; qi < 4; ++qi) {
#pragma unroll
        for (int mt = 0; mt < 4; ++mt) {
          f32x4 st = {};
          st = __builtin_amdgcn_mfma_f32_16x16x32_bf16(ak[mt][0], bq[qi][0], st, 0, 0, 0);
          st = __builtin_amdgcn_mfma_f32_16x16x32_bf16(ak[mt][1], bq[qi][1], st, 0, 0, 0);
          const float p0 = fexp2(st[0]), p1 = fexp2(st[1]);
          const float p2 = fexp2(st[2]), p3 = fexp2(st[3]);
          rs[qi] += (p0 + p1) + (p2 + p3);
          uint2 pw;
          pw.x = pkb(p0, p1);
          pw.y = pkb(p2, p3);
          const int col = (((mt * 2 + (quad >> 1)) ^ swzq) * 8) + (quad & 1) * 4;
          *(uint2*)&Pl[w][qi][c16][col] = pw;
        }
      }
    }
    asm volatile("s_waitcnt lgkmcnt(0)" ::: "memory");  // P writes visible (same wave)
    // ---- Phase B: O += P V (ap preloaded, bv streamed per nt) ----
    bf16x8 ap[4][2];
#pragma unroll
    for (int qi = 0; qi < 4; ++qi) {
      ap[qi][0] = *(const bf16x8*)&Pl[w][qi][c16][(quad ^ swzq) * 8];
      ap[qi][1] = *(const bf16x8*)&Pl[w][qi][c16][((4 + quad) ^ swzq) * 8];
    }
#pragma unroll
    for (int nt = 0; nt < 4; ++nt) {
      const int r = nt * 16 + c16;
      const bf16x8 bv0 = *(const bf16x8*)&Vt[r][(quad ^ swzq) * 8];
      const bf16x8 bv1 = *(const bf16x8*)&Vt[r][((4 + quad) ^ swzq) * 8];
#pragma unroll
      for (int qi = 0; qi < 4; ++qi) {
        acc[qi][nt] = __builtin_amdgcn_mfma_f32_16x16x32_bf16(ap[qi][0], bv0, acc[qi][nt], 0, 0, 0);
        acc[qi][nt] = __builtin_amdgcn_mfma_f32_16x16x32_bf16(ap[qi][1], bv1, acc[qi][nt], 0, 0, 0);
      }
    }
  }
  // softmax denominators: reduce over quads, broadcast via LDS
#pragma unroll
  for (int qi = 0; qi < 4; ++qi) {
    float t = rs[qi];
    t += __shfl_xor(t, 16, 64);
    t += __shfl_xor(t, 32, 64);
    if (quad == 0) Ll[w][qi][c16] = t;
  }
  asm volatile("s_waitcnt lgkmcnt(0)" ::: "memory");
#pragma unroll
  for (int qi = 0; qi < 4; ++qi) {
    const f32x4 lv = *(const f32x4*)&Ll[w][qi][quad * 4];
#pragma unroll
    for (int r = 0; r < 4; ++r) {
      const float inv = 1.0f / lv[r];
      const size_t rowbase = (size_t)(b * T + qbase + qi * 16 + quad * 4 + r) * DM + h * 64;
#pragma unroll
      for (int nt = 0; nt < 4; ++nt) {
        const size_t idx = rowbase + nt * 16 + c16;
        out[idx] = acc[qi][nt][r] * inv + res[idx];
      }
    }
  }
}

extern "C" void kernel_launch(void* const* d_in, const int* in_sizes, int n_in,
                              void* d_out, int out_size, void* d_ws, size_t ws_size,
                              hipStream_t stream) {
  const float* q = (const float*)d_in[0];
  const float* k = (const float*)d_in[1];
  const float* v = (const float*)d_in[2];
  const float* WQ = (const float*)d_in[3];
  const float* WK = (const float*)d_in[4];
  const float* WV = (const float*)d_in[5];
  char* ws = (char*)d_ws;
  const size_t PH = (size_t)8192 * 1024 * 2;   // bf16 activation buffer bytes
  const size_t WT = (size_t)1024 * 1024 * 2;
  // d_out doubles as scratch for 2 of the 3 bf16 X tensors (fully rewritten by flash).
  u16* XqB = (u16*)d_out;
  u16* XkB = (u16*)d_out + (size_t)8192 * 1024;
  u16* XvB = (u16*)(ws);
  u16* WtQ = (u16*)(ws + PH);
  u16* WtK = (u16*)(ws + PH + WT);
  u16* WtV = (u16*)(ws + PH + 2 * WT);
  u16* QH  = (u16*)(ws + PH + 3 * WT);
  u16* KH  = (u16*)(ws + 2 * PH + 3 * WT);
  u16* VHt = (u16*)(ws + 3 * PH + 3 * WT);

  xcvt<<<dim3(4096, 3), 256, 0, stream>>>(q, k, v, XqB, XkB, XvB);
  wt_kernel<<<dim3(16, 16, 3), 256, 0, stream>>>(WQ, WK, WV, WtQ, WtK, WtV);
  gemm_proj<<<dim3(512, 3), 256, 0, stream>>>(XqB, XkB, XvB, WtQ, WtK, WtV, QH, KH, VHt);
  flash_kernel<<<512, 256, 0, stream>>>(QH, KH, VHt, q, (float*)d_out);
}